// Round 17
// baseline (180.033 us; speedup 1.0000x reference)
//
#include <hip/hip_runtime.h>
#include <math.h>

#define ALPHA 0.2f
#define BKT 128      // rows per bucket
#define PCHUNK 4096  // edges per binA block
#define WT_PITCH 264 // ushorts per Wt row (256 + 8 pad; keeps 16B align, spreads banks)

using f32x4 = __attribute__((ext_vector_type(4))) float;
using s16x8 = __attribute__((ext_vector_type(8))) short;

__device__ __forceinline__ unsigned short f2bf(float x) {
  unsigned u = __float_as_uint(x);
  unsigned r = (u + 0x7FFFu + ((u >> 16) & 1u)) >> 16;
  return (unsigned short)r;
}
__device__ __forceinline__ float bflo(unsigned s) { return __uint_as_float(s << 16); }
__device__ __forceinline__ float bfhi(unsigned s) { return __uint_as_float(s & 0xFFFF0000u); }

// ---------------- zero bucket counters ----------------
__global__ void init_b(unsigned* bcnt, int n) {
  int i = blockIdx.x * blockDim.x + threadIdx.x;
  if (i < n) bcnt[i] = 0u;
}

// ---------------- MFMA bf16 GEMM h=seq@W fused with f1/f2 + bf16(h) ----------------
__global__ __launch_bounds__(256) void gemm_fused(
    const float* __restrict__ seq, const float* __restrict__ W,
    const float* __restrict__ a1w, const float* __restrict__ a1b,
    const float* __restrict__ a2w, const float* __restrict__ a2b,
    unsigned* __restrict__ hb, float* __restrict__ f1, float* __restrict__ f2, int N) {
  __shared__ unsigned short Wt[128][WT_PITCH];  // 67.6 KB
  const int tid = threadIdx.x;
  const int lane = tid & 63;
  const int wv = tid >> 6;    // wave 0..3
  const int lr = lane & 15;   // fragment row/col index
  const int lq = lane >> 4;   // k-group 0..3
  const int rowbase = blockIdx.x * 128;

  #pragma unroll
  for (int l = 0; l < 32; ++l) {
    int fi = tid + l * 256;
    int kk = fi >> 5, cg = fi & 31;
    float4 v = *reinterpret_cast<const float4*>(W + (size_t)kk * 128 + cg * 4);
    Wt[cg * 4 + 0][kk] = f2bf(v.x);
    Wt[cg * 4 + 1][kk] = f2bf(v.y);
    Wt[cg * 4 + 2][kk] = f2bf(v.z);
    Wt[cg * 4 + 3][kk] = f2bf(v.w);
  }
  __syncthreads();

  int r0 = rowbase + wv * 32 + lr;
  int r1 = r0 + 16;
  int gr0 = (r0 < N - 1) ? r0 : (N - 1);
  int gr1 = (r1 < N - 1) ? r1 : (N - 1);
  const float* arow0 = seq + (size_t)gr0 * 256 + lq * 8;
  const float* arow1 = seq + (size_t)gr1 * 256 + lq * 8;

  f32x4 acc[2][8] = {};

  float4 p00 = *reinterpret_cast<const float4*>(arow0);
  float4 p01 = *reinterpret_cast<const float4*>(arow0 + 4);
  float4 p10 = *reinterpret_cast<const float4*>(arow1);
  float4 p11 = *reinterpret_cast<const float4*>(arow1 + 4);

  for (int ks = 0; ks < 8; ++ks) {
    s16x8 a0, a1;
    a0[0] = (short)f2bf(p00.x); a0[1] = (short)f2bf(p00.y);
    a0[2] = (short)f2bf(p00.z); a0[3] = (short)f2bf(p00.w);
    a0[4] = (short)f2bf(p01.x); a0[5] = (short)f2bf(p01.y);
    a0[6] = (short)f2bf(p01.z); a0[7] = (short)f2bf(p01.w);
    a1[0] = (short)f2bf(p10.x); a1[1] = (short)f2bf(p10.y);
    a1[2] = (short)f2bf(p10.z); a1[3] = (short)f2bf(p10.w);
    a1[4] = (short)f2bf(p11.x); a1[5] = (short)f2bf(p11.y);
    a1[6] = (short)f2bf(p11.z); a1[7] = (short)f2bf(p11.w);

    if (ks < 7) {
      const float* n0 = arow0 + (ks + 1) * 32;
      const float* n1 = arow1 + (ks + 1) * 32;
      p00 = *reinterpret_cast<const float4*>(n0);
      p01 = *reinterpret_cast<const float4*>(n0 + 4);
      p10 = *reinterpret_cast<const float4*>(n1);
      p11 = *reinterpret_cast<const float4*>(n1 + 4);
    }

    #pragma unroll
    for (int nf = 0; nf < 8; ++nf) {
      s16x8 b = *reinterpret_cast<const s16x8*>(&Wt[nf * 16 + lr][ks * 32 + lq * 8]);
      acc[0][nf] = __builtin_amdgcn_mfma_f32_16x16x32_bf16(a0, b, acc[0][nf], 0, 0, 0);
      acc[1][nf] = __builtin_amdgcn_mfma_f32_16x16x32_bf16(a1, b, acc[1][nf], 0, 0, 0);
    }
  }

  float w1[8], w2[8];
  #pragma unroll
  for (int nf = 0; nf < 8; ++nf) { w1[nf] = a1w[nf * 16 + lr]; w2[nf] = a2w[nf * 16 + lr]; }
  float b1s = a1b[0], b2s = a2b[0];

  #pragma unroll
  for (int mf = 0; mf < 2; ++mf) {
    #pragma unroll
    for (int reg = 0; reg < 4; ++reg) {
      int gr = rowbase + wv * 32 + mf * 16 + lq * 4 + reg;
      float hv[8];
      float p1 = 0.0f, p2 = 0.0f;
      #pragma unroll
      for (int nf = 0; nf < 8; ++nf) {
        hv[nf] = acc[mf][nf][reg];
        p1 += hv[nf] * w1[nf];
        p2 += hv[nf] * w2[nf];
      }
      #pragma unroll
      for (int off = 1; off <= 8; off <<= 1) {
        p1 += __shfl_xor(p1, off);
        p2 += __shfl_xor(p2, off);
      }
      bool rowok = gr < N;
      #pragma unroll
      for (int nf = 0; nf < 8; ++nf) {
        int mine = (int)f2bf(hv[nf]);
        int oth = __shfl_xor(mine, 1);
        if (rowok && !(lr & 1)) {
          unsigned packed = (unsigned)mine | ((unsigned)oth << 16);
          hb[(size_t)gr * 64 + nf * 8 + (lr >> 1)] = packed;
        }
      }
      if (rowok && lr == 0) { f1[gr] = p1 + b1s; f2[gr] = p2 + b2s; }
    }
  }
}

// ---------------- bucket histogram: LDS-aggregated ----------------
__global__ __launch_bounds__(256) void bhist(const int* __restrict__ row,
                                             unsigned* __restrict__ bcnt_g, int E, int NBKT) {
  __shared__ unsigned h[512];
  const int tid = threadIdx.x;
  for (int i = tid; i < 512; i += 256) h[i] = 0u;
  __syncthreads();
  int base = (blockIdx.x * 256 + tid) * 4;
  if (base + 3 < E) {
    int4 r = *reinterpret_cast<const int4*>(row + base);
    atomicAdd(&h[r.x >> 7], 1u);
    atomicAdd(&h[r.y >> 7], 1u);
    atomicAdd(&h[r.z >> 7], 1u);
    atomicAdd(&h[r.w >> 7], 1u);
  } else {
    for (int i = base; i < E; ++i) atomicAdd(&h[row[i] >> 7], 1u);
  }
  __syncthreads();
  for (int b = tid; b < NBKT; b += 256) {
    unsigned c = h[b];
    if (c) atomicAdd(&bcnt_g[b], c);
  }
}

// ---------------- bucket scan: 1 block; bstart + tail ----------------
__global__ __launch_bounds__(256) void bscan(const unsigned* __restrict__ bcnt,
                                             unsigned* __restrict__ bstart,
                                             unsigned* __restrict__ tail, int NBKT) {
  __shared__ unsigned wsum[4];
  const int tid = threadIdx.x;
  const int lane = tid & 63, wv = tid >> 6;
  unsigned a0 = (2 * tid < NBKT) ? bcnt[2 * tid] : 0u;
  unsigned a1 = (2 * tid + 1 < NBKT) ? bcnt[2 * tid + 1] : 0u;
  unsigned pairv = a0 + a1;
  unsigned x = pairv;
  #pragma unroll
  for (int d = 1; d < 64; d <<= 1) {
    unsigned y = __shfl_up(x, d);
    if (lane >= d) x += y;
  }
  if (lane == 63) wsum[wv] = x;
  __syncthreads();
  unsigned woff = 0;
  for (int i = 0; i < wv; ++i) woff += wsum[i];
  unsigned exclp = x + woff - pairv;  // exclusive prefix of pair
  if (2 * tid < NBKT)     { bstart[2 * tid] = exclp;       tail[2 * tid] = exclp; }
  if (2 * tid + 1 < NBKT) { bstart[2 * tid + 1] = exclp + a0; tail[2 * tid + 1] = exclp + a0; }
  if (tid == 255) bstart[NBKT] = woff + wsum[3];  // total = E
}

// ---------------- Pass A: LDS radix binning into row-buckets ----------------
__global__ __launch_bounds__(256) void binA(const int* __restrict__ row,
                                            const int* __restrict__ col,
                                            const float* __restrict__ w,
                                            const float* __restrict__ f1,
                                            const float* __restrict__ f2,
                                            unsigned* __restrict__ tail,
                                            uint2* __restrict__ stg, int E, int NBKT) {
  __shared__ unsigned bcnt[512];
  __shared__ unsigned bcur[512];
  __shared__ uint2 sstg[PCHUNK];
  const int tid = threadIdx.x;
  const int lane = tid & 63, wv = tid >> 6;
  const int base = blockIdx.x * PCHUNK;

  for (int i = tid; i < 512; i += 256) bcnt[i] = 0u;
  __syncthreads();

  float vv[16];
  unsigned pk[16];
  #pragma unroll
  for (int l = 0; l < 16; ++l) {
    int idx = base + tid + l * 256;
    if (idx < E) {
      int r = row[idx], c = col[idx];
      float x = f1[r] + f2[c];
      x = x > 0.0f ? x : ALPHA * x;
      x *= w[idx];
      vv[l] = x;
      pk[l] = ((unsigned)c << 16) | (unsigned)r;
      atomicAdd(&bcnt[r >> 7], 1u);
    } else {
      pk[l] = 0xFFFFFFFFu;
    }
  }
  __syncthreads();

  unsigned a0 = bcnt[2 * tid], a1 = bcnt[2 * tid + 1];
  unsigned pairv = a0 + a1;
  unsigned x = pairv;
  #pragma unroll
  for (int d = 1; d < 64; d <<= 1) {
    unsigned y = __shfl_up(x, d);
    if (lane >= d) x += y;
  }
  __shared__ unsigned wsum[4];
  if (lane == 63) wsum[wv] = x;
  __syncthreads();
  unsigned woff = 0;
  for (int i = 0; i < wv; ++i) woff += wsum[i];
  unsigned exclp = x + woff - pairv;
  bcur[2 * tid] = exclp;
  bcur[2 * tid + 1] = exclp + a0;
  __syncthreads();

  #pragma unroll
  for (int l = 0; l < 16; ++l) {
    if (pk[l] != 0xFFFFFFFFu) {
      unsigned b = (pk[l] & 0xFFFFu) >> 7;
      unsigned p = atomicAdd(&bcur[b], 1u);
      sstg[p] = make_uint2(__float_as_uint(vv[l]), pk[l]);
    }
  }
  __syncthreads();

  for (int b = tid; b < NBKT; b += 256) {
    unsigned c = bcnt[b];
    if (c) {
      unsigned g = atomicAdd(&tail[b], c);
      bcnt[b] = g - (bcur[b] - c);  // delta = globalstart - ldsstart
    }
  }
  __syncthreads();

  int ne = E - base; if (ne > PCHUNK) ne = PCHUNK;
  for (int i = tid; i < ne; i += 256) {
    uint2 e2 = sstg[i];
    unsigned b = (e2.y & 0xFFFFu) >> 7;
    stg[i + bcnt[b]] = e2;
  }
}

// ---------------- Pass B: per-row count+scan -> rowstart; place into CSR ----------------
__global__ __launch_bounds__(256) void binB(const unsigned* __restrict__ bstart,
                                            const uint2* __restrict__ stg,
                                            uint2* __restrict__ eb,
                                            unsigned* __restrict__ rowstart, int N, int NBKT) {
  const int b = blockIdx.x;
  const int r0 = b * BKT;
  int r1 = r0 + BKT; if (r1 > N) r1 = N;
  const int nrows = r1 - r0;
  __shared__ unsigned cnt[BKT];
  __shared__ unsigned cur[BKT];
  const int tid = threadIdx.x;
  if (tid < BKT) cnt[tid] = 0u;
  __syncthreads();
  const int sA = (int)bstart[b], eA = (int)bstart[b + 1];

  for (int i = sA + tid; i < eA; i += 256) {
    atomicAdd(&cnt[stg[i].y & 127u], 1u);
  }
  __syncthreads();

  unsigned orig = (tid < BKT) ? cnt[tid] : 0u;
  for (int off = 1; off < BKT; off <<= 1) {
    unsigned v = 0u;
    if (tid < BKT && tid >= off) v = cnt[tid - off];
    __syncthreads();
    if (tid < BKT) cnt[tid] += v;
    __syncthreads();
  }
  if (tid < nrows) {
    unsigned start = (unsigned)sA + cnt[tid] - orig;  // exclusive
    cur[tid] = start;
    rowstart[r0 + tid] = start;
  }
  if (b == NBKT - 1 && tid == 0) rowstart[N] = (unsigned)eA;
  __syncthreads();

  for (int i = sA + tid; i < eA; i += 256) {
    uint2 e2 = stg[i];
    unsigned rl = e2.y & 127u;
    unsigned c = e2.y >> 16;
    unsigned slot = atomicAdd(&cur[rl], 1u);
    eb[slot] = make_uint2(e2.x, c);
  }
}

// ---------------- fused softmax + pull SpMM ----------------
// One wave per row. Single edge pass: per 32-edge chunk, unrolled i=0..7,
// quarter qw broadcast-loads eb[s0+4i+qw], computes cf=exp(x-m) itself (no
// shuffle, no redundant exp), accumulates dsum and cf*h. rd applied at the
// end (scalar factors commute). Unroll exposes 8 independent gathers.
__global__ __launch_bounds__(256) void spmm(const unsigned* __restrict__ rowstart,
                                            const uint2* __restrict__ eb,
                                            const unsigned* __restrict__ hb,
                                            const float* __restrict__ bias,
                                            float* __restrict__ out, int N) {
  int wid = (blockIdx.x * 256 + threadIdx.x) >> 6;
  int lane = threadIdx.x & 63;
  if (wid >= N) return;
  const int s = (int)rowstart[wid], e = (int)rowstart[wid + 1];
  const int qw = lane >> 4;
  const int ql = lane & 15;

  // ---- phase 1: row max (lane-strided) ----
  float m = -3.4e38f;
  for (int j = s + lane; j < e; j += 64) m = fmaxf(m, __uint_as_float(eb[j].x));
  #pragma unroll
  for (int off = 32; off > 0; off >>= 1) m = fmaxf(m, __shfl_xor(m, off));

  // ---- single fused pass: denom + accumulate ----
  float acc[8] = {};
  float dsum = 0.0f;
  for (int s0 = s; s0 < e; s0 += 32) {
    int nloc = e - s0; if (nloc > 32) nloc = 32;
    #pragma unroll
    for (int i = 0; i < 8; ++i) {
      int k = 4 * i + qw;
      bool v = k < nloc;           // uniform within a quarter
      if (v) {
        uint2 t = eb[s0 + k];      // quarter-broadcast load
        float cf = __expf(__uint_as_float(t.x) - m);
        dsum += cf;
        const uint4 g = *reinterpret_cast<const uint4*>(hb + (size_t)t.y * 64 + ql * 4);
        acc[0] += cf * bflo(g.x); acc[1] += cf * bfhi(g.x);
        acc[2] += cf * bflo(g.y); acc[3] += cf * bfhi(g.y);
        acc[4] += cf * bflo(g.z); acc[5] += cf * bfhi(g.z);
        acc[6] += cf * bflo(g.w); acc[7] += cf * bfhi(g.w);
      }
    }
  }

  // ---- denom: each lane holds its quarter's partial; reduce across quarters ----
  dsum += __shfl_xor(dsum, 16);
  dsum += __shfl_xor(dsum, 32);
  float rd = 1.0f / fmaxf(dsum, 1e-38f);

  // ---- scale + cross-quarter reduction ----
  #pragma unroll
  for (int i = 0; i < 8; ++i) {
    acc[i] *= rd;
    acc[i] += __shfl_xor(acc[i], 16);
    acc[i] += __shfl_xor(acc[i], 32);
  }

  if (qw == 0) {
    const int d0 = ql * 8;
    float4 b0 = *reinterpret_cast<const float4*>(bias + d0);
    float4 b1 = *reinterpret_cast<const float4*>(bias + d0 + 4);
    float4 o0, o1;
    o0.x = fmaxf(acc[0] + b0.x, 0.0f); o0.y = fmaxf(acc[1] + b0.y, 0.0f);
    o0.z = fmaxf(acc[2] + b0.z, 0.0f); o0.w = fmaxf(acc[3] + b0.w, 0.0f);
    o1.x = fmaxf(acc[4] + b1.x, 0.0f); o1.y = fmaxf(acc[5] + b1.y, 0.0f);
    o1.z = fmaxf(acc[6] + b1.z, 0.0f); o1.w = fmaxf(acc[7] + b1.w, 0.0f);
    *reinterpret_cast<float4*>(out + (size_t)wid * 128 + d0) = o0;
    *reinterpret_cast<float4*>(out + (size_t)wid * 128 + d0 + 4) = o1;
  }
}

extern "C" void kernel_launch(void* const* d_in, const int* in_sizes, int n_in,
                              void* d_out, int out_size, void* d_ws, size_t ws_size,
                              hipStream_t stream) {
  const float* seq    = (const float*)d_in[0];
  const int*   erow   = (const int*)d_in[1];
  const int*   ecol   = (const int*)d_in[2];
  const float* weight = (const float*)d_in[3];
  const float* W      = (const float*)d_in[4];
  const float* a1w    = (const float*)d_in[5];
  const float* a1b    = (const float*)d_in[6];
  const float* a2w    = (const float*)d_in[7];
  const float* a2b    = (const float*)d_in[8];
  const float* bias   = (const float*)d_in[9];
  const int N = in_sizes[0] / 256;
  const int E = in_sizes[1];
  float* out = (float*)d_out;

  char* p = (char*)d_ws;
  auto alloc = [&](size_t bytes) -> char* {
    char* q = p;
    p += (bytes + 255) & ~(size_t)255;
    return q;
  };
  unsigned* hb       = (unsigned*)alloc((size_t)N * 64 * 4);
  float*    f1       = (float*)alloc((size_t)N * 4);
  float*    f2       = (float*)alloc((size_t)N * 4);
  unsigned* rowstart = (unsigned*)alloc((size_t)(N + 1) * 4);
  const int NBKT = (N + BKT - 1) / BKT;
  unsigned* bcnt     = (unsigned*)alloc((size_t)512 * 4);
  unsigned* bstart   = (unsigned*)alloc((size_t)(NBKT + 1) * 4);
  unsigned* tail     = (unsigned*)alloc((size_t)NBKT * 4);
  uint2*    stg      = (uint2*)alloc((size_t)E * 8);
  uint2*    eb       = (uint2*)alloc((size_t)E * 8);

  init_b<<<2, 256, 0, stream>>>(bcnt, 512);
  gemm_fused<<<(N + 127) / 128, 256, 0, stream>>>(seq, W, a1w, a1b, a2w, a2b, hb, f1, f2, N);
  bhist<<<(E / 4 + 255) / 256, 256, 0, stream>>>(erow, bcnt, E, NBKT);
  bscan<<<1, 256, 0, stream>>>(bcnt, bstart, tail, NBKT);
  binA<<<(E + PCHUNK - 1) / PCHUNK, 256, 0, stream>>>(erow, ecol, weight, f1, f2, tail, stg, E, NBKT);
  binB<<<NBKT, 256, 0, stream>>>(bstart, stg, eb, rowstart, N, NBKT);
  spmm<<<(N * 64 + 255) / 256, 256, 0, stream>>>(rowstart, eb, hb, bias, out, N);
}

// Round 18
// 179.124 us; speedup vs baseline: 1.0051x; 1.0051x over previous
//
#include <hip/hip_runtime.h>
#include <math.h>

#define ALPHA 0.2f
#define BKT 128      // rows per bucket
#define PCHUNK 4096  // edges per binA block
#define WT_PITCH 264 // ushorts per Wt row (256 + 8 pad; keeps 16B align, spreads banks)

using f32x4 = __attribute__((ext_vector_type(4))) float;
using s16x8 = __attribute__((ext_vector_type(8))) short;

__device__ __forceinline__ unsigned short f2bf(float x) {
  unsigned u = __float_as_uint(x);
  unsigned r = (u + 0x7FFFu + ((u >> 16) & 1u)) >> 16;
  return (unsigned short)r;
}
__device__ __forceinline__ float bflo(unsigned s) { return __uint_as_float(s << 16); }
__device__ __forceinline__ float bfhi(unsigned s) { return __uint_as_float(s & 0xFFFF0000u); }

// ---------------- zero bucket counters ----------------
__global__ void init_b(unsigned* bcnt, int n) {
  int i = blockIdx.x * blockDim.x + threadIdx.x;
  if (i < n) bcnt[i] = 0u;
}

// ---------------- MFMA bf16 GEMM h=seq@W fused with f1/f2 + bf16(h) ----------------
__global__ __launch_bounds__(256) void gemm_fused(
    const float* __restrict__ seq, const float* __restrict__ W,
    const float* __restrict__ a1w, const float* __restrict__ a1b,
    const float* __restrict__ a2w, const float* __restrict__ a2b,
    unsigned* __restrict__ hb, float* __restrict__ f1, float* __restrict__ f2, int N) {
  __shared__ unsigned short Wt[128][WT_PITCH];  // 67.6 KB
  const int tid = threadIdx.x;
  const int lane = tid & 63;
  const int wv = tid >> 6;    // wave 0..3
  const int lr = lane & 15;   // fragment row/col index
  const int lq = lane >> 4;   // k-group 0..3
  const int rowbase = blockIdx.x * 128;

  #pragma unroll
  for (int l = 0; l < 32; ++l) {
    int fi = tid + l * 256;
    int kk = fi >> 5, cg = fi & 31;
    float4 v = *reinterpret_cast<const float4*>(W + (size_t)kk * 128 + cg * 4);
    Wt[cg * 4 + 0][kk] = f2bf(v.x);
    Wt[cg * 4 + 1][kk] = f2bf(v.y);
    Wt[cg * 4 + 2][kk] = f2bf(v.z);
    Wt[cg * 4 + 3][kk] = f2bf(v.w);
  }
  __syncthreads();

  int r0 = rowbase + wv * 32 + lr;
  int r1 = r0 + 16;
  int gr0 = (r0 < N - 1) ? r0 : (N - 1);
  int gr1 = (r1 < N - 1) ? r1 : (N - 1);
  const float* arow0 = seq + (size_t)gr0 * 256 + lq * 8;
  const float* arow1 = seq + (size_t)gr1 * 256 + lq * 8;

  f32x4 acc[2][8] = {};

  float4 p00 = *reinterpret_cast<const float4*>(arow0);
  float4 p01 = *reinterpret_cast<const float4*>(arow0 + 4);
  float4 p10 = *reinterpret_cast<const float4*>(arow1);
  float4 p11 = *reinterpret_cast<const float4*>(arow1 + 4);

  for (int ks = 0; ks < 8; ++ks) {
    s16x8 a0, a1;
    a0[0] = (short)f2bf(p00.x); a0[1] = (short)f2bf(p00.y);
    a0[2] = (short)f2bf(p00.z); a0[3] = (short)f2bf(p00.w);
    a0[4] = (short)f2bf(p01.x); a0[5] = (short)f2bf(p01.y);
    a0[6] = (short)f2bf(p01.z); a0[7] = (short)f2bf(p01.w);
    a1[0] = (short)f2bf(p10.x); a1[1] = (short)f2bf(p10.y);
    a1[2] = (short)f2bf(p10.z); a1[3] = (short)f2bf(p10.w);
    a1[4] = (short)f2bf(p11.x); a1[5] = (short)f2bf(p11.y);
    a1[6] = (short)f2bf(p11.z); a1[7] = (short)f2bf(p11.w);

    if (ks < 7) {
      const float* n0 = arow0 + (ks + 1) * 32;
      const float* n1 = arow1 + (ks + 1) * 32;
      p00 = *reinterpret_cast<const float4*>(n0);
      p01 = *reinterpret_cast<const float4*>(n0 + 4);
      p10 = *reinterpret_cast<const float4*>(n1);
      p11 = *reinterpret_cast<const float4*>(n1 + 4);
    }

    #pragma unroll
    for (int nf = 0; nf < 8; ++nf) {
      s16x8 b = *reinterpret_cast<const s16x8*>(&Wt[nf * 16 + lr][ks * 32 + lq * 8]);
      acc[0][nf] = __builtin_amdgcn_mfma_f32_16x16x32_bf16(a0, b, acc[0][nf], 0, 0, 0);
      acc[1][nf] = __builtin_amdgcn_mfma_f32_16x16x32_bf16(a1, b, acc[1][nf], 0, 0, 0);
    }
  }

  float w1[8], w2[8];
  #pragma unroll
  for (int nf = 0; nf < 8; ++nf) { w1[nf] = a1w[nf * 16 + lr]; w2[nf] = a2w[nf * 16 + lr]; }
  float b1s = a1b[0], b2s = a2b[0];

  #pragma unroll
  for (int mf = 0; mf < 2; ++mf) {
    #pragma unroll
    for (int reg = 0; reg < 4; ++reg) {
      int gr = rowbase + wv * 32 + mf * 16 + lq * 4 + reg;
      float hv[8];
      float p1 = 0.0f, p2 = 0.0f;
      #pragma unroll
      for (int nf = 0; nf < 8; ++nf) {
        hv[nf] = acc[mf][nf][reg];
        p1 += hv[nf] * w1[nf];
        p2 += hv[nf] * w2[nf];
      }
      #pragma unroll
      for (int off = 1; off <= 8; off <<= 1) {
        p1 += __shfl_xor(p1, off);
        p2 += __shfl_xor(p2, off);
      }
      bool rowok = gr < N;
      #pragma unroll
      for (int nf = 0; nf < 8; ++nf) {
        int mine = (int)f2bf(hv[nf]);
        int oth = __shfl_xor(mine, 1);
        if (rowok && !(lr & 1)) {
          unsigned packed = (unsigned)mine | ((unsigned)oth << 16);
          hb[(size_t)gr * 64 + nf * 8 + (lr >> 1)] = packed;
        }
      }
      if (rowok && lr == 0) { f1[gr] = p1 + b1s; f2[gr] = p2 + b2s; }
    }
  }
}

// ---------------- bucket histogram: LDS-aggregated ----------------
__global__ __launch_bounds__(256) void bhist(const int* __restrict__ row,
                                             unsigned* __restrict__ bcnt_g, int E, int NBKT) {
  __shared__ unsigned h[512];
  const int tid = threadIdx.x;
  for (int i = tid; i < 512; i += 256) h[i] = 0u;
  __syncthreads();
  int base = (blockIdx.x * 256 + tid) * 4;
  if (base + 3 < E) {
    int4 r = *reinterpret_cast<const int4*>(row + base);
    atomicAdd(&h[r.x >> 7], 1u);
    atomicAdd(&h[r.y >> 7], 1u);
    atomicAdd(&h[r.z >> 7], 1u);
    atomicAdd(&h[r.w >> 7], 1u);
  } else {
    for (int i = base; i < E; ++i) atomicAdd(&h[row[i] >> 7], 1u);
  }
  __syncthreads();
  for (int b = tid; b < NBKT; b += 256) {
    unsigned c = h[b];
    if (c) atomicAdd(&bcnt_g[b], c);
  }
}

// ---------------- bucket scan: 1 block; bstart + tail ----------------
__global__ __launch_bounds__(256) void bscan(const unsigned* __restrict__ bcnt,
                                             unsigned* __restrict__ bstart,
                                             unsigned* __restrict__ tail, int NBKT) {
  __shared__ unsigned wsum[4];
  const int tid = threadIdx.x;
  const int lane = tid & 63, wv = tid >> 6;
  unsigned a0 = (2 * tid < NBKT) ? bcnt[2 * tid] : 0u;
  unsigned a1 = (2 * tid + 1 < NBKT) ? bcnt[2 * tid + 1] : 0u;
  unsigned pairv = a0 + a1;
  unsigned x = pairv;
  #pragma unroll
  for (int d = 1; d < 64; d <<= 1) {
    unsigned y = __shfl_up(x, d);
    if (lane >= d) x += y;
  }
  if (lane == 63) wsum[wv] = x;
  __syncthreads();
  unsigned woff = 0;
  for (int i = 0; i < wv; ++i) woff += wsum[i];
  unsigned exclp = x + woff - pairv;  // exclusive prefix of pair
  if (2 * tid < NBKT)     { bstart[2 * tid] = exclp;       tail[2 * tid] = exclp; }
  if (2 * tid + 1 < NBKT) { bstart[2 * tid + 1] = exclp + a0; tail[2 * tid + 1] = exclp + a0; }
  if (tid == 255) bstart[NBKT] = woff + wsum[3];  // total = E
}

// ---------------- Pass A: LDS radix binning into row-buckets ----------------
__global__ __launch_bounds__(256) void binA(const int* __restrict__ row,
                                            const int* __restrict__ col,
                                            const float* __restrict__ w,
                                            const float* __restrict__ f1,
                                            const float* __restrict__ f2,
                                            unsigned* __restrict__ tail,
                                            uint2* __restrict__ stg, int E, int NBKT) {
  __shared__ unsigned bcnt[512];
  __shared__ unsigned bcur[512];
  __shared__ uint2 sstg[PCHUNK];
  const int tid = threadIdx.x;
  const int lane = tid & 63, wv = tid >> 6;
  const int base = blockIdx.x * PCHUNK;

  for (int i = tid; i < 512; i += 256) bcnt[i] = 0u;
  __syncthreads();

  float vv[16];
  unsigned pk[16];
  #pragma unroll
  for (int l = 0; l < 16; ++l) {
    int idx = base + tid + l * 256;
    if (idx < E) {
      int r = row[idx], c = col[idx];
      float x = f1[r] + f2[c];
      x = x > 0.0f ? x : ALPHA * x;
      x *= w[idx];
      vv[l] = x;
      pk[l] = ((unsigned)c << 16) | (unsigned)r;
      atomicAdd(&bcnt[r >> 7], 1u);
    } else {
      pk[l] = 0xFFFFFFFFu;
    }
  }
  __syncthreads();

  unsigned a0 = bcnt[2 * tid], a1 = bcnt[2 * tid + 1];
  unsigned pairv = a0 + a1;
  unsigned x = pairv;
  #pragma unroll
  for (int d = 1; d < 64; d <<= 1) {
    unsigned y = __shfl_up(x, d);
    if (lane >= d) x += y;
  }
  __shared__ unsigned wsum[4];
  if (lane == 63) wsum[wv] = x;
  __syncthreads();
  unsigned woff = 0;
  for (int i = 0; i < wv; ++i) woff += wsum[i];
  unsigned exclp = x + woff - pairv;
  bcur[2 * tid] = exclp;
  bcur[2 * tid + 1] = exclp + a0;
  __syncthreads();

  #pragma unroll
  for (int l = 0; l < 16; ++l) {
    if (pk[l] != 0xFFFFFFFFu) {
      unsigned b = (pk[l] & 0xFFFFu) >> 7;
      unsigned p = atomicAdd(&bcur[b], 1u);
      sstg[p] = make_uint2(__float_as_uint(vv[l]), pk[l]);
    }
  }
  __syncthreads();

  for (int b = tid; b < NBKT; b += 256) {
    unsigned c = bcnt[b];
    if (c) {
      unsigned g = atomicAdd(&tail[b], c);
      bcnt[b] = g - (bcur[b] - c);  // delta = globalstart - ldsstart
    }
  }
  __syncthreads();

  int ne = E - base; if (ne > PCHUNK) ne = PCHUNK;
  for (int i = tid; i < ne; i += 256) {
    uint2 e2 = sstg[i];
    unsigned b = (e2.y & 0xFFFFu) >> 7;
    stg[i + bcnt[b]] = e2;
  }
}

// ---------------- Pass B: per-row count+scan -> rowstart; place into CSR ----------------
__global__ __launch_bounds__(256) void binB(const unsigned* __restrict__ bstart,
                                            const uint2* __restrict__ stg,
                                            uint2* __restrict__ eb,
                                            unsigned* __restrict__ rowstart, int N, int NBKT) {
  const int b = blockIdx.x;
  const int r0 = b * BKT;
  int r1 = r0 + BKT; if (r1 > N) r1 = N;
  const int nrows = r1 - r0;
  __shared__ unsigned cnt[BKT];
  __shared__ unsigned cur[BKT];
  const int tid = threadIdx.x;
  if (tid < BKT) cnt[tid] = 0u;
  __syncthreads();
  const int sA = (int)bstart[b], eA = (int)bstart[b + 1];

  for (int i = sA + tid; i < eA; i += 256) {
    atomicAdd(&cnt[stg[i].y & 127u], 1u);
  }
  __syncthreads();

  unsigned orig = (tid < BKT) ? cnt[tid] : 0u;
  for (int off = 1; off < BKT; off <<= 1) {
    unsigned v = 0u;
    if (tid < BKT && tid >= off) v = cnt[tid - off];
    __syncthreads();
    if (tid < BKT) cnt[tid] += v;
    __syncthreads();
  }
  if (tid < nrows) {
    unsigned start = (unsigned)sA + cnt[tid] - orig;  // exclusive
    cur[tid] = start;
    rowstart[r0 + tid] = start;
  }
  if (b == NBKT - 1 && tid == 0) rowstart[N] = (unsigned)eA;
  __syncthreads();

  for (int i = sA + tid; i < eA; i += 256) {
    uint2 e2 = stg[i];
    unsigned rl = e2.y & 127u;
    unsigned c = e2.y >> 16;
    unsigned slot = atomicAdd(&cur[rl], 1u);
    eb[slot] = make_uint2(e2.x, c);
  }
}

// ---------------- fused softmax + pull SpMM ----------------
// One wave per row. Branch-free chunked pass: chunks of 32 edges, unrolled
// 8 steps, ALL loads unconditional (tail steps clamp the index to the row's
// first edge and zero the coefficient) -> compiler keeps 8 gather chains in
// flight. Denom fused (per-quarter dsum, reduced at end; rd applied after).
__global__ __launch_bounds__(256) void spmm(const unsigned* __restrict__ rowstart,
                                            const uint2* __restrict__ eb,
                                            const unsigned* __restrict__ hb,
                                            const float* __restrict__ bias,
                                            float* __restrict__ out, int N) {
  int wid = (blockIdx.x * 256 + threadIdx.x) >> 6;
  int lane = threadIdx.x & 63;
  if (wid >= N) return;
  const int s = (int)rowstart[wid], e = (int)rowstart[wid + 1];
  const int qw = lane >> 4;
  const int ql = lane & 15;

  // ---- phase 1: row max (lane-strided) ----
  float m = -3.4e38f;
  for (int j = s + lane; j < e; j += 64) m = fmaxf(m, __uint_as_float(eb[j].x));
  #pragma unroll
  for (int off = 32; off > 0; off >>= 1) m = fmaxf(m, __shfl_xor(m, off));

  // ---- single fused pass: denom + accumulate, branch-free ----
  float acc[8] = {};
  float dsum = 0.0f;
  const int nCh = (e - s + 31) >> 5;  // wave-uniform
  for (int c = 0; c < nCh; ++c) {
    int base = s + c * 32 + qw;
    #pragma unroll
    for (int i = 0; i < 8; ++i) {
      int k = base + 4 * i;
      bool live = k < e;
      int idx = live ? k : s;          // always a valid eb slot
      uint2 t = eb[idx];               // unconditional quarter-broadcast load
      float cf = live ? __expf(__uint_as_float(t.x) - m) : 0.0f;
      dsum += cf;
      const uint4 g = *reinterpret_cast<const uint4*>(hb + (size_t)t.y * 64 + ql * 4);
      acc[0] += cf * bflo(g.x); acc[1] += cf * bfhi(g.x);
      acc[2] += cf * bflo(g.y); acc[3] += cf * bfhi(g.y);
      acc[4] += cf * bflo(g.z); acc[5] += cf * bfhi(g.z);
      acc[6] += cf * bflo(g.w); acc[7] += cf * bfhi(g.w);
    }
  }

  // ---- denom: per-quarter partials -> full wave ----
  dsum += __shfl_xor(dsum, 16);
  dsum += __shfl_xor(dsum, 32);
  float rd = 1.0f / fmaxf(dsum, 1e-38f);

  // ---- scale + cross-quarter reduction ----
  #pragma unroll
  for (int i = 0; i < 8; ++i) {
    acc[i] *= rd;
    acc[i] += __shfl_xor(acc[i], 16);
    acc[i] += __shfl_xor(acc[i], 32);
  }

  if (qw == 0) {
    const int d0 = ql * 8;
    float4 b0 = *reinterpret_cast<const float4*>(bias + d0);
    float4 b1 = *reinterpret_cast<const float4*>(bias + d0 + 4);
    float4 o0, o1;
    o0.x = fmaxf(acc[0] + b0.x, 0.0f); o0.y = fmaxf(acc[1] + b0.y, 0.0f);
    o0.z = fmaxf(acc[2] + b0.z, 0.0f); o0.w = fmaxf(acc[3] + b0.w, 0.0f);
    o1.x = fmaxf(acc[4] + b1.x, 0.0f); o1.y = fmaxf(acc[5] + b1.y, 0.0f);
    o1.z = fmaxf(acc[6] + b1.z, 0.0f); o1.w = fmaxf(acc[7] + b1.w, 0.0f);
    *reinterpret_cast<float4*>(out + (size_t)wid * 128 + d0) = o0;
    *reinterpret_cast<float4*>(out + (size_t)wid * 128 + d0 + 4) = o1;
  }
}

extern "C" void kernel_launch(void* const* d_in, const int* in_sizes, int n_in,
                              void* d_out, int out_size, void* d_ws, size_t ws_size,
                              hipStream_t stream) {
  const float* seq    = (const float*)d_in[0];
  const int*   erow   = (const int*)d_in[1];
  const int*   ecol   = (const int*)d_in[2];
  const float* weight = (const float*)d_in[3];
  const float* W      = (const float*)d_in[4];
  const float* a1w    = (const float*)d_in[5];
  const float* a1b    = (const float*)d_in[6];
  const float* a2w    = (const float*)d_in[7];
  const float* a2b    = (const float*)d_in[8];
  const float* bias   = (const float*)d_in[9];
  const int N = in_sizes[0] / 256;
  const int E = in_sizes[1];
  float* out = (float*)d_out;

  char* p = (char*)d_ws;
  auto alloc = [&](size_t bytes) -> char* {
    char* q = p;
    p += (bytes + 255) & ~(size_t)255;
    return q;
  };
  unsigned* hb       = (unsigned*)alloc((size_t)N * 64 * 4);
  float*    f1       = (float*)alloc((size_t)N * 4);
  float*    f2       = (float*)alloc((size_t)N * 4);
  unsigned* rowstart = (unsigned*)alloc((size_t)(N + 1) * 4);
  const int NBKT = (N + BKT - 1) / BKT;
  unsigned* bcnt     = (unsigned*)alloc((size_t)512 * 4);
  unsigned* bstart   = (unsigned*)alloc((size_t)(NBKT + 1) * 4);
  unsigned* tail     = (unsigned*)alloc((size_t)NBKT * 4);
  uint2*    stg      = (uint2*)alloc((size_t)E * 8);
  uint2*    eb       = (uint2*)alloc((size_t)E * 8);

  init_b<<<2, 256, 0, stream>>>(bcnt, 512);
  gemm_fused<<<(N + 127) / 128, 256, 0, stream>>>(seq, W, a1w, a1b, a2w, a2b, hb, f1, f2, N);
  bhist<<<(E / 4 + 255) / 256, 256, 0, stream>>>(erow, bcnt, E, NBKT);
  bscan<<<1, 256, 0, stream>>>(bcnt, bstart, tail, NBKT);
  binA<<<(E + PCHUNK - 1) / PCHUNK, 256, 0, stream>>>(erow, ecol, weight, f1, f2, tail, stg, E, NBKT);
  binB<<<NBKT, 256, 0, stream>>>(bstart, stg, eb, rowstart, N, NBKT);
  spmm<<<(N * 64 + 255) / 256, 256, 0, stream>>>(rowstart, eb, hb, bias, out, N);
}

// Round 19
// 174.603 us; speedup vs baseline: 1.0311x; 1.0259x over previous
//
#include <hip/hip_runtime.h>
#include <math.h>

#define ALPHA 0.2f
#define BKT 128      // rows per bucket
#define PCHUNK 4096  // edges per binA block
#define WT_PITCH 264 // ushorts per Wt row (256 + 8 pad; keeps 16B align, spreads banks)

using f32x4 = __attribute__((ext_vector_type(4))) float;
using s16x8 = __attribute__((ext_vector_type(8))) short;

__device__ __forceinline__ unsigned short f2bf(float x) {
  unsigned u = __float_as_uint(x);
  unsigned r = (u + 0x7FFFu + ((u >> 16) & 1u)) >> 16;
  return (unsigned short)r;
}
__device__ __forceinline__ float bflo(unsigned s) { return __uint_as_float(s << 16); }
__device__ __forceinline__ float bfhi(unsigned s) { return __uint_as_float(s & 0xFFFF0000u); }
__device__ __forceinline__ unsigned fkey(float x) {
  unsigned b = __float_as_uint(x);
  return (b & 0x80000000u) ? ~b : (b | 0x80000000u);
}
__device__ __forceinline__ float kinv(unsigned k) {
  unsigned b = (k & 0x80000000u) ? (k & 0x7FFFFFFFu) : ~k;
  return __uint_as_float(b);
}

// ---------------- zero bucket counters ----------------
__global__ void init_b(unsigned* bcnt, int n) {
  int i = blockIdx.x * blockDim.x + threadIdx.x;
  if (i < n) bcnt[i] = 0u;
}

// ---------------- MFMA bf16 GEMM h=seq@W fused with f1/f2 + bf16(h) ----------------
__global__ __launch_bounds__(256) void gemm_fused(
    const float* __restrict__ seq, const float* __restrict__ W,
    const float* __restrict__ a1w, const float* __restrict__ a1b,
    const float* __restrict__ a2w, const float* __restrict__ a2b,
    unsigned* __restrict__ hb, float* __restrict__ f1, float* __restrict__ f2, int N) {
  __shared__ unsigned short Wt[128][WT_PITCH];  // 67.6 KB
  const int tid = threadIdx.x;
  const int lane = tid & 63;
  const int wv = tid >> 6;    // wave 0..3
  const int lr = lane & 15;   // fragment row/col index
  const int lq = lane >> 4;   // k-group 0..3
  const int rowbase = blockIdx.x * 128;

  #pragma unroll
  for (int l = 0; l < 32; ++l) {
    int fi = tid + l * 256;
    int kk = fi >> 5, cg = fi & 31;
    float4 v = *reinterpret_cast<const float4*>(W + (size_t)kk * 128 + cg * 4);
    Wt[cg * 4 + 0][kk] = f2bf(v.x);
    Wt[cg * 4 + 1][kk] = f2bf(v.y);
    Wt[cg * 4 + 2][kk] = f2bf(v.z);
    Wt[cg * 4 + 3][kk] = f2bf(v.w);
  }
  __syncthreads();

  int r0 = rowbase + wv * 32 + lr;
  int r1 = r0 + 16;
  int gr0 = (r0 < N - 1) ? r0 : (N - 1);
  int gr1 = (r1 < N - 1) ? r1 : (N - 1);
  const float* arow0 = seq + (size_t)gr0 * 256 + lq * 8;
  const float* arow1 = seq + (size_t)gr1 * 256 + lq * 8;

  f32x4 acc[2][8] = {};

  float4 p00 = *reinterpret_cast<const float4*>(arow0);
  float4 p01 = *reinterpret_cast<const float4*>(arow0 + 4);
  float4 p10 = *reinterpret_cast<const float4*>(arow1);
  float4 p11 = *reinterpret_cast<const float4*>(arow1 + 4);

  for (int ks = 0; ks < 8; ++ks) {
    s16x8 a0, a1;
    a0[0] = (short)f2bf(p00.x); a0[1] = (short)f2bf(p00.y);
    a0[2] = (short)f2bf(p00.z); a0[3] = (short)f2bf(p00.w);
    a0[4] = (short)f2bf(p01.x); a0[5] = (short)f2bf(p01.y);
    a0[6] = (short)f2bf(p01.z); a0[7] = (short)f2bf(p01.w);
    a1[0] = (short)f2bf(p10.x); a1[1] = (short)f2bf(p10.y);
    a1[2] = (short)f2bf(p10.z); a1[3] = (short)f2bf(p10.w);
    a1[4] = (short)f2bf(p11.x); a1[5] = (short)f2bf(p11.y);
    a1[6] = (short)f2bf(p11.z); a1[7] = (short)f2bf(p11.w);

    if (ks < 7) {
      const float* n0 = arow0 + (ks + 1) * 32;
      const float* n1 = arow1 + (ks + 1) * 32;
      p00 = *reinterpret_cast<const float4*>(n0);
      p01 = *reinterpret_cast<const float4*>(n0 + 4);
      p10 = *reinterpret_cast<const float4*>(n1);
      p11 = *reinterpret_cast<const float4*>(n1 + 4);
    }

    #pragma unroll
    for (int nf = 0; nf < 8; ++nf) {
      s16x8 b = *reinterpret_cast<const s16x8*>(&Wt[nf * 16 + lr][ks * 32 + lq * 8]);
      acc[0][nf] = __builtin_amdgcn_mfma_f32_16x16x32_bf16(a0, b, acc[0][nf], 0, 0, 0);
      acc[1][nf] = __builtin_amdgcn_mfma_f32_16x16x32_bf16(a1, b, acc[1][nf], 0, 0, 0);
    }
  }

  float w1[8], w2[8];
  #pragma unroll
  for (int nf = 0; nf < 8; ++nf) { w1[nf] = a1w[nf * 16 + lr]; w2[nf] = a2w[nf * 16 + lr]; }
  float b1s = a1b[0], b2s = a2b[0];

  #pragma unroll
  for (int mf = 0; mf < 2; ++mf) {
    #pragma unroll
    for (int reg = 0; reg < 4; ++reg) {
      int gr = rowbase + wv * 32 + mf * 16 + lq * 4 + reg;
      float hv[8];
      float p1 = 0.0f, p2 = 0.0f;
      #pragma unroll
      for (int nf = 0; nf < 8; ++nf) {
        hv[nf] = acc[mf][nf][reg];
        p1 += hv[nf] * w1[nf];
        p2 += hv[nf] * w2[nf];
      }
      #pragma unroll
      for (int off = 1; off <= 8; off <<= 1) {
        p1 += __shfl_xor(p1, off);
        p2 += __shfl_xor(p2, off);
      }
      bool rowok = gr < N;
      #pragma unroll
      for (int nf = 0; nf < 8; ++nf) {
        int mine = (int)f2bf(hv[nf]);
        int oth = __shfl_xor(mine, 1);
        if (rowok && !(lr & 1)) {
          unsigned packed = (unsigned)mine | ((unsigned)oth << 16);
          hb[(size_t)gr * 64 + nf * 8 + (lr >> 1)] = packed;
        }
      }
      if (rowok && lr == 0) { f1[gr] = p1 + b1s; f2[gr] = p2 + b2s; }
    }
  }
}

// ---------------- bucket histogram: LDS-aggregated ----------------
__global__ __launch_bounds__(256) void bhist(const int* __restrict__ row,
                                             unsigned* __restrict__ bcnt_g, int E, int NBKT) {
  __shared__ unsigned h[512];
  const int tid = threadIdx.x;
  for (int i = tid; i < 512; i += 256) h[i] = 0u;
  __syncthreads();
  int base = (blockIdx.x * 256 + tid) * 4;
  if (base + 3 < E) {
    int4 r = *reinterpret_cast<const int4*>(row + base);
    atomicAdd(&h[r.x >> 7], 1u);
    atomicAdd(&h[r.y >> 7], 1u);
    atomicAdd(&h[r.z >> 7], 1u);
    atomicAdd(&h[r.w >> 7], 1u);
  } else {
    for (int i = base; i < E; ++i) atomicAdd(&h[row[i] >> 7], 1u);
  }
  __syncthreads();
  for (int b = tid; b < NBKT; b += 256) {
    unsigned c = h[b];
    if (c) atomicAdd(&bcnt_g[b], c);
  }
}

// ---------------- bucket scan: 1 block; bstart + tail ----------------
__global__ __launch_bounds__(256) void bscan(const unsigned* __restrict__ bcnt,
                                             unsigned* __restrict__ bstart,
                                             unsigned* __restrict__ tail, int NBKT) {
  __shared__ unsigned wsum[4];
  const int tid = threadIdx.x;
  const int lane = tid & 63, wv = tid >> 6;
  unsigned a0 = (2 * tid < NBKT) ? bcnt[2 * tid] : 0u;
  unsigned a1 = (2 * tid + 1 < NBKT) ? bcnt[2 * tid + 1] : 0u;
  unsigned pairv = a0 + a1;
  unsigned x = pairv;
  #pragma unroll
  for (int d = 1; d < 64; d <<= 1) {
    unsigned y = __shfl_up(x, d);
    if (lane >= d) x += y;
  }
  if (lane == 63) wsum[wv] = x;
  __syncthreads();
  unsigned woff = 0;
  for (int i = 0; i < wv; ++i) woff += wsum[i];
  unsigned exclp = x + woff - pairv;  // exclusive prefix of pair
  if (2 * tid < NBKT)     { bstart[2 * tid] = exclp;       tail[2 * tid] = exclp; }
  if (2 * tid + 1 < NBKT) { bstart[2 * tid + 1] = exclp + a0; tail[2 * tid + 1] = exclp + a0; }
  if (tid == 255) bstart[NBKT] = woff + wsum[3];  // total = E
}

// ---------------- Pass A: LDS radix binning into row-buckets ----------------
__global__ __launch_bounds__(256) void binA(const int* __restrict__ row,
                                            const int* __restrict__ col,
                                            const float* __restrict__ w,
                                            const float* __restrict__ f1,
                                            const float* __restrict__ f2,
                                            unsigned* __restrict__ tail,
                                            uint2* __restrict__ stg, int E, int NBKT) {
  __shared__ unsigned bcnt[512];
  __shared__ unsigned bcur[512];
  __shared__ uint2 sstg[PCHUNK];
  const int tid = threadIdx.x;
  const int lane = tid & 63, wv = tid >> 6;
  const int base = blockIdx.x * PCHUNK;

  for (int i = tid; i < 512; i += 256) bcnt[i] = 0u;
  __syncthreads();

  float vv[16];
  unsigned pk[16];
  #pragma unroll
  for (int l = 0; l < 16; ++l) {
    int idx = base + tid + l * 256;
    if (idx < E) {
      int r = row[idx], c = col[idx];
      float x = f1[r] + f2[c];
      x = x > 0.0f ? x : ALPHA * x;
      x *= w[idx];
      vv[l] = x;
      pk[l] = ((unsigned)c << 16) | (unsigned)r;
      atomicAdd(&bcnt[r >> 7], 1u);
    } else {
      pk[l] = 0xFFFFFFFFu;
    }
  }
  __syncthreads();

  unsigned a0 = bcnt[2 * tid], a1 = bcnt[2 * tid + 1];
  unsigned pairv = a0 + a1;
  unsigned x = pairv;
  #pragma unroll
  for (int d = 1; d < 64; d <<= 1) {
    unsigned y = __shfl_up(x, d);
    if (lane >= d) x += y;
  }
  __shared__ unsigned wsum[4];
  if (lane == 63) wsum[wv] = x;
  __syncthreads();
  unsigned woff = 0;
  for (int i = 0; i < wv; ++i) woff += wsum[i];
  unsigned exclp = x + woff - pairv;
  bcur[2 * tid] = exclp;
  bcur[2 * tid + 1] = exclp + a0;
  __syncthreads();

  #pragma unroll
  for (int l = 0; l < 16; ++l) {
    if (pk[l] != 0xFFFFFFFFu) {
      unsigned b = (pk[l] & 0xFFFFu) >> 7;
      unsigned p = atomicAdd(&bcur[b], 1u);
      sstg[p] = make_uint2(__float_as_uint(vv[l]), pk[l]);
    }
  }
  __syncthreads();

  for (int b = tid; b < NBKT; b += 256) {
    unsigned c = bcnt[b];
    if (c) {
      unsigned g = atomicAdd(&tail[b], c);
      bcnt[b] = g - (bcur[b] - c);  // delta = globalstart - ldsstart
    }
  }
  __syncthreads();

  int ne = E - base; if (ne > PCHUNK) ne = PCHUNK;
  for (int i = tid; i < ne; i += 256) {
    uint2 e2 = sstg[i];
    unsigned b = (e2.y & 0xFFFFu) >> 7;
    stg[i + bcnt[b]] = e2;
  }
}

// ---------------- Pass B: rowstart + softmax (max/exp/denom) + CSR place ----------------
// Extended: besides counting rows and placing edges, computes per-row max
// (LDS atomicMax on fkey), stores exp(v-m) in eb.x, accumulates per-row denom
// (LDS float atomicAdd), and writes rdArr[row]=1/denom. spmm becomes gather-only.
__global__ __launch_bounds__(256) void binB(const unsigned* __restrict__ bstart,
                                            const uint2* __restrict__ stg,
                                            uint2* __restrict__ eb,
                                            unsigned* __restrict__ rowstart,
                                            float* __restrict__ rdArr, int N, int NBKT) {
  const int b = blockIdx.x;
  const int r0 = b * BKT;
  int r1 = r0 + BKT; if (r1 > N) r1 = N;
  const int nrows = r1 - r0;
  __shared__ unsigned cnt[BKT];
  __shared__ unsigned cur[BKT];
  __shared__ unsigned mkey[BKT];
  __shared__ float dsum[BKT];
  const int tid = threadIdx.x;
  if (tid < BKT) { cnt[tid] = 0u; mkey[tid] = 0u; dsum[tid] = 0.0f; }
  __syncthreads();
  const int sA = (int)bstart[b], eA = (int)bstart[b + 1];

  // pass 1: per-row counts + per-row max (cache-hot staged bucket)
  for (int i = sA + tid; i < eA; i += 256) {
    uint2 e2 = stg[i];
    unsigned rl = e2.y & 127u;
    atomicAdd(&cnt[rl], 1u);
    atomicMax(&mkey[rl], fkey(__uint_as_float(e2.x)));
  }
  __syncthreads();

  // inclusive Hillis-Steele scan over cnt[0..127]
  unsigned orig = (tid < BKT) ? cnt[tid] : 0u;
  for (int off = 1; off < BKT; off <<= 1) {
    unsigned v = 0u;
    if (tid < BKT && tid >= off) v = cnt[tid - off];
    __syncthreads();
    if (tid < BKT) cnt[tid] += v;
    __syncthreads();
  }
  if (tid < nrows) {
    unsigned start = (unsigned)sA + cnt[tid] - orig;  // exclusive
    cur[tid] = start;
    rowstart[r0 + tid] = start;
  }
  if (b == NBKT - 1 && tid == 0) rowstart[N] = (unsigned)eA;
  __syncthreads();

  // pass 2: exp + denom accumulate + place into exact CSR slots (eb.x = exp(v-m))
  for (int i = sA + tid; i < eA; i += 256) {
    uint2 e2 = stg[i];
    unsigned rl = e2.y & 127u;
    unsigned c = e2.y >> 16;
    float ex = __expf(__uint_as_float(e2.x) - kinv(mkey[rl]));
    atomicAdd(&dsum[rl], ex);
    unsigned slot = atomicAdd(&cur[rl], 1u);
    eb[slot] = make_uint2(__float_as_uint(ex), c);
  }
  __syncthreads();

  if (tid < nrows) rdArr[r0 + tid] = 1.0f / fmaxf(dsum[tid], 1e-38f);
}

// ---------------- pull SpMM (gather-only; softmax precomputed in binB) ----------------
// R15-measured structure (57.5us): one wave per row, 4 quarter-waves x uint4
// gathers, wave-uniform bk loop, shfl broadcast of (cf,col). exp/max/denom
// passes removed -- cf comes pre-exponentiated in eb.x, rd from rdArr.
__global__ __launch_bounds__(256) void spmm(const unsigned* __restrict__ rowstart,
                                            const float* __restrict__ rdArr,
                                            const uint2* __restrict__ eb,
                                            const unsigned* __restrict__ hb,
                                            const float* __restrict__ bias,
                                            float* __restrict__ out, int N) {
  int wid = (blockIdx.x * 256 + threadIdx.x) >> 6;
  int lane = threadIdx.x & 63;
  if (wid >= N) return;
  const int s = (int)rowstart[wid], e = (int)rowstart[wid + 1];
  const int qw = lane >> 4;
  const int ql = lane & 15;
  const float rd = rdArr[wid];

  float acc[8] = {};
  int j0 = s + lane;
  float cf_reg = 0.0f;
  int c_reg = 0;
  if (j0 < e) {
    uint2 t = eb[j0];
    cf_reg = __uint_as_float(t.x) * rd;
    c_reg = (int)t.y;
  }
  for (int base = s; base < e; base += 64) {
    if (base != s) {  // reload for rare multi-chunk rows
      int j = base + lane;
      if (j < e) {
        uint2 t = eb[j];
        cf_reg = __uint_as_float(t.x) * rd;
        c_reg = (int)t.y;
      } else {
        cf_reg = 0.0f; c_reg = 0;
      }
    }
    int nloc = e - base; if (nloc > 64) nloc = 64;
    for (int bk = 0; bk < nloc; bk += 4) {  // wave-uniform trip count
      int k = bk + qw;                       // may exceed nloc by up to 3
      int ksrc = (k < 64) ? k : 0;           // clamp shfl source
      float cfk = __shfl(cf_reg, ksrc);      // full exec mask here
      int ck = __shfl(c_reg, ksrc);
      if (k < nloc) {
        const uint4 hv = *reinterpret_cast<const uint4*>(hb + (size_t)ck * 64 + ql * 4);
        acc[0] += cfk * bflo(hv.x); acc[1] += cfk * bfhi(hv.x);
        acc[2] += cfk * bflo(hv.y); acc[3] += cfk * bfhi(hv.y);
        acc[4] += cfk * bflo(hv.z); acc[5] += cfk * bfhi(hv.z);
        acc[6] += cfk * bflo(hv.w); acc[7] += cfk * bfhi(hv.w);
      }
    }
  }

  #pragma unroll
  for (int i = 0; i < 8; ++i) {
    acc[i] += __shfl_xor(acc[i], 16);
    acc[i] += __shfl_xor(acc[i], 32);
  }

  if (qw == 0) {
    const int d0 = ql * 8;
    float4 b0 = *reinterpret_cast<const float4*>(bias + d0);
    float4 b1 = *reinterpret_cast<const float4*>(bias + d0 + 4);
    float4 o0, o1;
    o0.x = fmaxf(acc[0] + b0.x, 0.0f); o0.y = fmaxf(acc[1] + b0.y, 0.0f);
    o0.z = fmaxf(acc[2] + b0.z, 0.0f); o0.w = fmaxf(acc[3] + b0.w, 0.0f);
    o1.x = fmaxf(acc[4] + b1.x, 0.0f); o1.y = fmaxf(acc[5] + b1.y, 0.0f);
    o1.z = fmaxf(acc[6] + b1.z, 0.0f); o1.w = fmaxf(acc[7] + b1.w, 0.0f);
    *reinterpret_cast<float4*>(out + (size_t)wid * 128 + d0) = o0;
    *reinterpret_cast<float4*>(out + (size_t)wid * 128 + d0 + 4) = o1;
  }
}

extern "C" void kernel_launch(void* const* d_in, const int* in_sizes, int n_in,
                              void* d_out, int out_size, void* d_ws, size_t ws_size,
                              hipStream_t stream) {
  const float* seq    = (const float*)d_in[0];
  const int*   erow   = (const int*)d_in[1];
  const int*   ecol   = (const int*)d_in[2];
  const float* weight = (const float*)d_in[3];
  const float* W      = (const float*)d_in[4];
  const float* a1w    = (const float*)d_in[5];
  const float* a1b    = (const float*)d_in[6];
  const float* a2w    = (const float*)d_in[7];
  const float* a2b    = (const float*)d_in[8];
  const float* bias   = (const float*)d_in[9];
  const int N = in_sizes[0] / 256;
  const int E = in_sizes[1];
  float* out = (float*)d_out;

  char* p = (char*)d_ws;
  auto alloc = [&](size_t bytes) -> char* {
    char* q = p;
    p += (bytes + 255) & ~(size_t)255;
    return q;
  };
  unsigned* hb       = (unsigned*)alloc((size_t)N * 64 * 4);
  float*    f1       = (float*)alloc((size_t)N * 4);
  float*    f2       = (float*)alloc((size_t)N * 4);
  unsigned* rowstart = (unsigned*)alloc((size_t)(N + 1) * 4);
  float*    rdArr    = (float*)alloc((size_t)N * 4);
  const int NBKT = (N + BKT - 1) / BKT;
  unsigned* bcnt     = (unsigned*)alloc((size_t)512 * 4);
  unsigned* bstart   = (unsigned*)alloc((size_t)(NBKT + 1) * 4);
  unsigned* tail     = (unsigned*)alloc((size_t)NBKT * 4);
  uint2*    stg      = (uint2*)alloc((size_t)E * 8);
  uint2*    eb       = (uint2*)alloc((size_t)E * 8);

  init_b<<<2, 256, 0, stream>>>(bcnt, 512);
  gemm_fused<<<(N + 127) / 128, 256, 0, stream>>>(seq, W, a1w, a1b, a2w, a2b, hb, f1, f2, N);
  bhist<<<(E / 4 + 255) / 256, 256, 0, stream>>>(erow, bcnt, E, NBKT);
  bscan<<<1, 256, 0, stream>>>(bcnt, bstart, tail, NBKT);
  binA<<<(E + PCHUNK - 1) / PCHUNK, 256, 0, stream>>>(erow, ecol, weight, f1, f2, tail, stg, E, NBKT);
  binB<<<NBKT, 256, 0, stream>>>(bstart, stg, eb, rowstart, rdArr, N, NBKT);
  spmm<<<(N * 64 + 255) / 256, 256, 0, stream>>>(rowstart, rdArr, eb, hb, bias, out, N);
}

// Round 20
// 171.066 us; speedup vs baseline: 1.0524x; 1.0207x over previous
//
#include <hip/hip_runtime.h>
#include <math.h>

#define ALPHA 0.2f
#define BKT 128      // rows per bucket
#define PCHUNK 4096  // edges per binA block
#define WT_PITCH 264 // ushorts per Wt row (256 + 8 pad; keeps 16B align, spreads banks)

using f32x4 = __attribute__((ext_vector_type(4))) float;
using s16x8 = __attribute__((ext_vector_type(8))) short;

__device__ __forceinline__ unsigned short f2bf(float x) {
  unsigned u = __float_as_uint(x);
  unsigned r = (u + 0x7FFFu + ((u >> 16) & 1u)) >> 16;
  return (unsigned short)r;
}
__device__ __forceinline__ float bflo(unsigned s) { return __uint_as_float(s << 16); }
__device__ __forceinline__ float bfhi(unsigned s) { return __uint_as_float(s & 0xFFFF0000u); }
__device__ __forceinline__ unsigned fkey(float x) {
  unsigned b = __float_as_uint(x);
  return (b & 0x80000000u) ? ~b : (b | 0x80000000u);
}
__device__ __forceinline__ float kinv(unsigned k) {
  unsigned b = (k & 0x80000000u) ? (k & 0x7FFFFFFFu) : ~k;
  return __uint_as_float(b);
}

// ---------------- zero bucket counters ----------------
__global__ void init_b(unsigned* bcnt, int n) {
  int i = blockIdx.x * blockDim.x + threadIdx.x;
  if (i < n) bcnt[i] = 0u;
}

// ---------------- MFMA bf16 GEMM h=seq@W fused with f1/f2 + bf16(h) ----------------
__global__ __launch_bounds__(256) void gemm_fused(
    const float* __restrict__ seq, const float* __restrict__ W,
    const float* __restrict__ a1w, const float* __restrict__ a1b,
    const float* __restrict__ a2w, const float* __restrict__ a2b,
    unsigned* __restrict__ hb, float* __restrict__ f1, float* __restrict__ f2, int N) {
  __shared__ unsigned short Wt[128][WT_PITCH];  // 67.6 KB
  const int tid = threadIdx.x;
  const int lane = tid & 63;
  const int wv = tid >> 6;    // wave 0..3
  const int lr = lane & 15;   // fragment row/col index
  const int lq = lane >> 4;   // k-group 0..3
  const int rowbase = blockIdx.x * 128;

  #pragma unroll
  for (int l = 0; l < 32; ++l) {
    int fi = tid + l * 256;
    int kk = fi >> 5, cg = fi & 31;
    float4 v = *reinterpret_cast<const float4*>(W + (size_t)kk * 128 + cg * 4);
    Wt[cg * 4 + 0][kk] = f2bf(v.x);
    Wt[cg * 4 + 1][kk] = f2bf(v.y);
    Wt[cg * 4 + 2][kk] = f2bf(v.z);
    Wt[cg * 4 + 3][kk] = f2bf(v.w);
  }
  __syncthreads();

  int r0 = rowbase + wv * 32 + lr;
  int r1 = r0 + 16;
  int gr0 = (r0 < N - 1) ? r0 : (N - 1);
  int gr1 = (r1 < N - 1) ? r1 : (N - 1);
  const float* arow0 = seq + (size_t)gr0 * 256 + lq * 8;
  const float* arow1 = seq + (size_t)gr1 * 256 + lq * 8;

  f32x4 acc[2][8] = {};

  float4 p00 = *reinterpret_cast<const float4*>(arow0);
  float4 p01 = *reinterpret_cast<const float4*>(arow0 + 4);
  float4 p10 = *reinterpret_cast<const float4*>(arow1);
  float4 p11 = *reinterpret_cast<const float4*>(arow1 + 4);

  for (int ks = 0; ks < 8; ++ks) {
    s16x8 a0, a1;
    a0[0] = (short)f2bf(p00.x); a0[1] = (short)f2bf(p00.y);
    a0[2] = (short)f2bf(p00.z); a0[3] = (short)f2bf(p00.w);
    a0[4] = (short)f2bf(p01.x); a0[5] = (short)f2bf(p01.y);
    a0[6] = (short)f2bf(p01.z); a0[7] = (short)f2bf(p01.w);
    a1[0] = (short)f2bf(p10.x); a1[1] = (short)f2bf(p10.y);
    a1[2] = (short)f2bf(p10.z); a1[3] = (short)f2bf(p10.w);
    a1[4] = (short)f2bf(p11.x); a1[5] = (short)f2bf(p11.y);
    a1[6] = (short)f2bf(p11.z); a1[7] = (short)f2bf(p11.w);

    if (ks < 7) {
      const float* n0 = arow0 + (ks + 1) * 32;
      const float* n1 = arow1 + (ks + 1) * 32;
      p00 = *reinterpret_cast<const float4*>(n0);
      p01 = *reinterpret_cast<const float4*>(n0 + 4);
      p10 = *reinterpret_cast<const float4*>(n1);
      p11 = *reinterpret_cast<const float4*>(n1 + 4);
    }

    #pragma unroll
    for (int nf = 0; nf < 8; ++nf) {
      s16x8 b = *reinterpret_cast<const s16x8*>(&Wt[nf * 16 + lr][ks * 32 + lq * 8]);
      acc[0][nf] = __builtin_amdgcn_mfma_f32_16x16x32_bf16(a0, b, acc[0][nf], 0, 0, 0);
      acc[1][nf] = __builtin_amdgcn_mfma_f32_16x16x32_bf16(a1, b, acc[1][nf], 0, 0, 0);
    }
  }

  float w1[8], w2[8];
  #pragma unroll
  for (int nf = 0; nf < 8; ++nf) { w1[nf] = a1w[nf * 16 + lr]; w2[nf] = a2w[nf * 16 + lr]; }
  float b1s = a1b[0], b2s = a2b[0];

  #pragma unroll
  for (int mf = 0; mf < 2; ++mf) {
    #pragma unroll
    for (int reg = 0; reg < 4; ++reg) {
      int gr = rowbase + wv * 32 + mf * 16 + lq * 4 + reg;
      float hv[8];
      float p1 = 0.0f, p2 = 0.0f;
      #pragma unroll
      for (int nf = 0; nf < 8; ++nf) {
        hv[nf] = acc[mf][nf][reg];
        p1 += hv[nf] * w1[nf];
        p2 += hv[nf] * w2[nf];
      }
      #pragma unroll
      for (int off = 1; off <= 8; off <<= 1) {
        p1 += __shfl_xor(p1, off);
        p2 += __shfl_xor(p2, off);
      }
      bool rowok = gr < N;
      #pragma unroll
      for (int nf = 0; nf < 8; ++nf) {
        int mine = (int)f2bf(hv[nf]);
        int oth = __shfl_xor(mine, 1);
        if (rowok && !(lr & 1)) {
          unsigned packed = (unsigned)mine | ((unsigned)oth << 16);
          hb[(size_t)gr * 64 + nf * 8 + (lr >> 1)] = packed;
        }
      }
      if (rowok && lr == 0) { f1[gr] = p1 + b1s; f2[gr] = p2 + b2s; }
    }
  }
}

// ---------------- bucket histogram: LDS-aggregated ----------------
__global__ __launch_bounds__(256) void bhist(const int* __restrict__ row,
                                             unsigned* __restrict__ bcnt_g, int E, int NBKT) {
  __shared__ unsigned h[512];
  const int tid = threadIdx.x;
  for (int i = tid; i < 512; i += 256) h[i] = 0u;
  __syncthreads();
  int base = (blockIdx.x * 256 + tid) * 4;
  if (base + 3 < E) {
    int4 r = *reinterpret_cast<const int4*>(row + base);
    atomicAdd(&h[r.x >> 7], 1u);
    atomicAdd(&h[r.y >> 7], 1u);
    atomicAdd(&h[r.z >> 7], 1u);
    atomicAdd(&h[r.w >> 7], 1u);
  } else {
    for (int i = base; i < E; ++i) atomicAdd(&h[row[i] >> 7], 1u);
  }
  __syncthreads();
  for (int b = tid; b < NBKT; b += 256) {
    unsigned c = h[b];
    if (c) atomicAdd(&bcnt_g[b], c);
  }
}

// ---------------- bucket scan: 1 block; bstart + tail ----------------
__global__ __launch_bounds__(256) void bscan(const unsigned* __restrict__ bcnt,
                                             unsigned* __restrict__ bstart,
                                             unsigned* __restrict__ tail, int NBKT) {
  __shared__ unsigned wsum[4];
  const int tid = threadIdx.x;
  const int lane = tid & 63, wv = tid >> 6;
  unsigned a0 = (2 * tid < NBKT) ? bcnt[2 * tid] : 0u;
  unsigned a1 = (2 * tid + 1 < NBKT) ? bcnt[2 * tid + 1] : 0u;
  unsigned pairv = a0 + a1;
  unsigned x = pairv;
  #pragma unroll
  for (int d = 1; d < 64; d <<= 1) {
    unsigned y = __shfl_up(x, d);
    if (lane >= d) x += y;
  }
  if (lane == 63) wsum[wv] = x;
  __syncthreads();
  unsigned woff = 0;
  for (int i = 0; i < wv; ++i) woff += wsum[i];
  unsigned exclp = x + woff - pairv;  // exclusive prefix of pair
  if (2 * tid < NBKT)     { bstart[2 * tid] = exclp;       tail[2 * tid] = exclp; }
  if (2 * tid + 1 < NBKT) { bstart[2 * tid + 1] = exclp + a0; tail[2 * tid + 1] = exclp + a0; }
  if (tid == 255) bstart[NBKT] = woff + wsum[3];  // total = E
}

// ---------------- Pass A: LDS radix binning into row-buckets ----------------
__global__ __launch_bounds__(256) void binA(const int* __restrict__ row,
                                            const int* __restrict__ col,
                                            const float* __restrict__ w,
                                            const float* __restrict__ f1,
                                            const float* __restrict__ f2,
                                            unsigned* __restrict__ tail,
                                            uint2* __restrict__ stg, int E, int NBKT) {
  __shared__ unsigned bcnt[512];
  __shared__ unsigned bcur[512];
  __shared__ uint2 sstg[PCHUNK];
  const int tid = threadIdx.x;
  const int lane = tid & 63, wv = tid >> 6;
  const int base = blockIdx.x * PCHUNK;

  for (int i = tid; i < 512; i += 256) bcnt[i] = 0u;
  __syncthreads();

  float vv[16];
  unsigned pk[16];
  #pragma unroll
  for (int l = 0; l < 16; ++l) {
    int idx = base + tid + l * 256;
    if (idx < E) {
      int r = row[idx], c = col[idx];
      float x = f1[r] + f2[c];
      x = x > 0.0f ? x : ALPHA * x;
      x *= w[idx];
      vv[l] = x;
      pk[l] = ((unsigned)c << 16) | (unsigned)r;
      atomicAdd(&bcnt[r >> 7], 1u);
    } else {
      pk[l] = 0xFFFFFFFFu;
    }
  }
  __syncthreads();

  unsigned a0 = bcnt[2 * tid], a1 = bcnt[2 * tid + 1];
  unsigned pairv = a0 + a1;
  unsigned x = pairv;
  #pragma unroll
  for (int d = 1; d < 64; d <<= 1) {
    unsigned y = __shfl_up(x, d);
    if (lane >= d) x += y;
  }
  __shared__ unsigned wsum[4];
  if (lane == 63) wsum[wv] = x;
  __syncthreads();
  unsigned woff = 0;
  for (int i = 0; i < wv; ++i) woff += wsum[i];
  unsigned exclp = x + woff - pairv;
  bcur[2 * tid] = exclp;
  bcur[2 * tid + 1] = exclp + a0;
  __syncthreads();

  #pragma unroll
  for (int l = 0; l < 16; ++l) {
    if (pk[l] != 0xFFFFFFFFu) {
      unsigned b = (pk[l] & 0xFFFFu) >> 7;
      unsigned p = atomicAdd(&bcur[b], 1u);
      sstg[p] = make_uint2(__float_as_uint(vv[l]), pk[l]);
    }
  }
  __syncthreads();

  for (int b = tid; b < NBKT; b += 256) {
    unsigned c = bcnt[b];
    if (c) {
      unsigned g = atomicAdd(&tail[b], c);
      bcnt[b] = g - (bcur[b] - c);  // delta = globalstart - ldsstart
    }
  }
  __syncthreads();

  int ne = E - base; if (ne > PCHUNK) ne = PCHUNK;
  for (int i = tid; i < ne; i += 256) {
    uint2 e2 = sstg[i];
    unsigned b = (e2.y & 0xFFFFu) >> 7;
    stg[i + bcnt[b]] = e2;
  }
}

// ---------------- Pass B: rowstart + softmax (max/exp/denom) + CSR place ----------------
__global__ __launch_bounds__(256) void binB(const unsigned* __restrict__ bstart,
                                            const uint2* __restrict__ stg,
                                            uint2* __restrict__ eb,
                                            unsigned* __restrict__ rowstart,
                                            float* __restrict__ rdArr, int N, int NBKT) {
  const int b = blockIdx.x;
  const int r0 = b * BKT;
  int r1 = r0 + BKT; if (r1 > N) r1 = N;
  const int nrows = r1 - r0;
  __shared__ unsigned cnt[BKT];
  __shared__ unsigned cur[BKT];
  __shared__ unsigned mkey[BKT];
  __shared__ float dsum[BKT];
  const int tid = threadIdx.x;
  if (tid < BKT) { cnt[tid] = 0u; mkey[tid] = 0u; dsum[tid] = 0.0f; }
  __syncthreads();
  const int sA = (int)bstart[b], eA = (int)bstart[b + 1];

  for (int i = sA + tid; i < eA; i += 256) {
    uint2 e2 = stg[i];
    unsigned rl = e2.y & 127u;
    atomicAdd(&cnt[rl], 1u);
    atomicMax(&mkey[rl], fkey(__uint_as_float(e2.x)));
  }
  __syncthreads();

  unsigned orig = (tid < BKT) ? cnt[tid] : 0u;
  for (int off = 1; off < BKT; off <<= 1) {
    unsigned v = 0u;
    if (tid < BKT && tid >= off) v = cnt[tid - off];
    __syncthreads();
    if (tid < BKT) cnt[tid] += v;
    __syncthreads();
  }
  if (tid < nrows) {
    unsigned start = (unsigned)sA + cnt[tid] - orig;  // exclusive
    cur[tid] = start;
    rowstart[r0 + tid] = start;
  }
  if (b == NBKT - 1 && tid == 0) rowstart[N] = (unsigned)eA;
  __syncthreads();

  for (int i = sA + tid; i < eA; i += 256) {
    uint2 e2 = stg[i];
    unsigned rl = e2.y & 127u;
    unsigned c = e2.y >> 16;
    float ex = __expf(__uint_as_float(e2.x) - kinv(mkey[rl]));
    atomicAdd(&dsum[rl], ex);
    unsigned slot = atomicAdd(&cur[rl], 1u);
    eb[slot] = make_uint2(__float_as_uint(ex), c);
  }
  __syncthreads();

  if (tid < nrows) rdArr[r0 + tid] = 1.0f / fmaxf(dsum[tid], 1e-38f);
}

// ---------------- pull SpMM (gather-only; softmax precomputed in binB) ----------------
// R15 structure + full/tail split: the full part (bk < nloc&~15) runs with
// ALL lanes provably in-bounds -> 4 unconditional gathers batched per
// iteration (16 in flight per wave with the 4 quarters); predicated tail
// handles the last <=3 sub-steps. Shuffles always at full exec mask.
__global__ __launch_bounds__(256) void spmm(const unsigned* __restrict__ rowstart,
                                            const float* __restrict__ rdArr,
                                            const uint2* __restrict__ eb,
                                            const unsigned* __restrict__ hb,
                                            const float* __restrict__ bias,
                                            float* __restrict__ out, int N) {
  int wid = (blockIdx.x * 256 + threadIdx.x) >> 6;
  int lane = threadIdx.x & 63;
  if (wid >= N) return;
  const int s = (int)rowstart[wid], e = (int)rowstart[wid + 1];
  const int qw = lane >> 4;
  const int ql = lane & 15;
  const float rd = rdArr[wid];

  float acc[8] = {};
  int j0 = s + lane;
  float cf_reg = 0.0f;
  int c_reg = 0;
  if (j0 < e) {
    uint2 t = eb[j0];
    cf_reg = __uint_as_float(t.x) * rd;
    c_reg = (int)t.y;
  }
  for (int base = s; base < e; base += 64) {
    if (base != s) {  // reload for rare multi-chunk rows
      int j = base + lane;
      if (j < e) {
        uint2 t = eb[j];
        cf_reg = __uint_as_float(t.x) * rd;
        c_reg = (int)t.y;
      } else {
        cf_reg = 0.0f; c_reg = 0;
      }
    }
    int nloc = e - base; if (nloc > 64) nloc = 64;
    const int full = nloc & ~15;  // all 4 sub-steps in-bounds for every lane
    int bk = 0;
    for (; bk < full; bk += 16) {
      float cf0 = __shfl(cf_reg, bk + qw);
      int   cc0 = __shfl(c_reg,  bk + qw);
      float cf1 = __shfl(cf_reg, bk + 4 + qw);
      int   cc1 = __shfl(c_reg,  bk + 4 + qw);
      float cf2 = __shfl(cf_reg, bk + 8 + qw);
      int   cc2 = __shfl(c_reg,  bk + 8 + qw);
      float cf3 = __shfl(cf_reg, bk + 12 + qw);
      int   cc3 = __shfl(c_reg,  bk + 12 + qw);
      const uint4 g0 = *reinterpret_cast<const uint4*>(hb + (size_t)cc0 * 64 + ql * 4);
      const uint4 g1 = *reinterpret_cast<const uint4*>(hb + (size_t)cc1 * 64 + ql * 4);
      const uint4 g2 = *reinterpret_cast<const uint4*>(hb + (size_t)cc2 * 64 + ql * 4);
      const uint4 g3 = *reinterpret_cast<const uint4*>(hb + (size_t)cc3 * 64 + ql * 4);
      acc[0] += cf0 * bflo(g0.x); acc[1] += cf0 * bfhi(g0.x);
      acc[2] += cf0 * bflo(g0.y); acc[3] += cf0 * bfhi(g0.y);
      acc[4] += cf0 * bflo(g0.z); acc[5] += cf0 * bfhi(g0.z);
      acc[6] += cf0 * bflo(g0.w); acc[7] += cf0 * bfhi(g0.w);
      acc[0] += cf1 * bflo(g1.x); acc[1] += cf1 * bfhi(g1.x);
      acc[2] += cf1 * bflo(g1.y); acc[3] += cf1 * bfhi(g1.y);
      acc[4] += cf1 * bflo(g1.z); acc[5] += cf1 * bfhi(g1.z);
      acc[6] += cf1 * bflo(g1.w); acc[7] += cf1 * bfhi(g1.w);
      acc[0] += cf2 * bflo(g2.x); acc[1] += cf2 * bfhi(g2.x);
      acc[2] += cf2 * bflo(g2.y); acc[3] += cf2 * bfhi(g2.y);
      acc[4] += cf2 * bflo(g2.z); acc[5] += cf2 * bfhi(g2.z);
      acc[6] += cf2 * bflo(g2.w); acc[7] += cf2 * bfhi(g2.w);
      acc[0] += cf3 * bflo(g3.x); acc[1] += cf3 * bfhi(g3.x);
      acc[2] += cf3 * bflo(g3.y); acc[3] += cf3 * bfhi(g3.y);
      acc[4] += cf3 * bflo(g3.z); acc[5] += cf3 * bfhi(g3.z);
      acc[6] += cf3 * bflo(g3.w); acc[7] += cf3 * bfhi(g3.w);
    }
    for (; bk < nloc; bk += 4) {  // tail: <=3 predicated sub-steps
      int k = bk + qw;
      int ksrc = (k < 64) ? k : 0;
      float cfk = __shfl(cf_reg, ksrc);
      int ck = __shfl(c_reg, ksrc);
      if (k < nloc) {
        const uint4 hv = *reinterpret_cast<const uint4*>(hb + (size_t)ck * 64 + ql * 4);
        acc[0] += cfk * bflo(hv.x); acc[1] += cfk * bfhi(hv.x);
        acc[2] += cfk * bflo(hv.y); acc[3] += cfk * bfhi(hv.y);
        acc[4] += cfk * bflo(hv.z); acc[5] += cfk * bfhi(hv.z);
        acc[6] += cfk * bflo(hv.w); acc[7] += cfk * bfhi(hv.w);
      }
    }
  }

  #pragma unroll
  for (int i = 0; i < 8; ++i) {
    acc[i] += __shfl_xor(acc[i], 16);
    acc[i] += __shfl_xor(acc[i], 32);
  }

  if (qw == 0) {
    const int d0 = ql * 8;
    float4 b0 = *reinterpret_cast<const float4*>(bias + d0);
    float4 b1 = *reinterpret_cast<const float4*>(bias + d0 + 4);
    float4 o0, o1;
    o0.x = fmaxf(acc[0] + b0.x, 0.0f); o0.y = fmaxf(acc[1] + b0.y, 0.0f);
    o0.z = fmaxf(acc[2] + b0.z, 0.0f); o0.w = fmaxf(acc[3] + b0.w, 0.0f);
    o1.x = fmaxf(acc[4] + b1.x, 0.0f); o1.y = fmaxf(acc[5] + b1.y, 0.0f);
    o1.z = fmaxf(acc[6] + b1.z, 0.0f); o1.w = fmaxf(acc[7] + b1.w, 0.0f);
    *reinterpret_cast<float4*>(out + (size_t)wid * 128 + d0) = o0;
    *reinterpret_cast<float4*>(out + (size_t)wid * 128 + d0 + 4) = o1;
  }
}

extern "C" void kernel_launch(void* const* d_in, const int* in_sizes, int n_in,
                              void* d_out, int out_size, void* d_ws, size_t ws_size,
                              hipStream_t stream) {
  const float* seq    = (const float*)d_in[0];
  const int*   erow   = (const int*)d_in[1];
  const int*   ecol   = (const int*)d_in[2];
  const float* weight = (const float*)d_in[3];
  const float* W      = (const float*)d_in[4];
  const float* a1w    = (const float*)d_in[5];
  const float* a1b    = (const float*)d_in[6];
  const float* a2w    = (const float*)d_in[7];
  const float* a2b    = (const float*)d_in[8];
  const float* bias   = (const float*)d_in[9];
  const int N = in_sizes[0] / 256;
  const int E = in_sizes[1];
  float* out = (float*)d_out;

  char* p = (char*)d_ws;
  auto alloc = [&](size_t bytes) -> char* {
    char* q = p;
    p += (bytes + 255) & ~(size_t)255;
    return q;
  };
  unsigned* hb       = (unsigned*)alloc((size_t)N * 64 * 4);
  float*    f1       = (float*)alloc((size_t)N * 4);
  float*    f2       = (float*)alloc((size_t)N * 4);
  unsigned* rowstart = (unsigned*)alloc((size_t)(N + 1) * 4);
  float*    rdArr    = (float*)alloc((size_t)N * 4);
  const int NBKT = (N + BKT - 1) / BKT;
  unsigned* bcnt     = (unsigned*)alloc((size_t)512 * 4);
  unsigned* bstart   = (unsigned*)alloc((size_t)(NBKT + 1) * 4);
  unsigned* tail     = (unsigned*)alloc((size_t)NBKT * 4);
  uint2*    stg      = (uint2*)alloc((size_t)E * 8);
  uint2*    eb       = (uint2*)alloc((size_t)E * 8);

  init_b<<<2, 256, 0, stream>>>(bcnt, 512);
  gemm_fused<<<(N + 127) / 128, 256, 0, stream>>>(seq, W, a1w, a1b, a2w, a2b, hb, f1, f2, N);
  bhist<<<(E / 4 + 255) / 256, 256, 0, stream>>>(erow, bcnt, E, NBKT);
  bscan<<<1, 256, 0, stream>>>(bcnt, bstart, tail, NBKT);
  binA<<<(E + PCHUNK - 1) / PCHUNK, 256, 0, stream>>>(erow, ecol, weight, f1, f2, tail, stg, E, NBKT);
  binB<<<NBKT, 256, 0, stream>>>(bstart, stg, eb, rowstart, rdArr, N, NBKT);
  spmm<<<(N * 64 + 255) / 256, 256, 0, stream>>>(rowstart, rdArr, eb, hb, bias, out, N);
}